// Round 1
// baseline (853.108 us; speedup 1.0000x reference)
//
#include <hip/hip_runtime.h>
#include <stdint.h>

// MS-SSIM + L1 fused loss, MI355X.
// Strategy: separable truncated Gaussian convs, fused per-tile kernel.
//  - 15 grouped-conv channels collapse to 7 (channel,sigma) pairs + 3 L1 convs.
//  - Tile 64x64/block, halo 16, x/y staged as bf16 in LDS (63KB total LDS).
//  - H-pass: 8-col strips, b128 window loads, register sliding FMA.
//  - V-pass: 1col x 8row strips, b32 column reads (stride 68 -> 2-way only).
//  - Truncated radii per sigma (weights < 1e-8 of sum dropped): ok at 2% tol.

#define TILE 64
#define HALO 16
#define HA   96      // halo extent (TILE + 2*HALO)
#define XSTR 96      // ushort stride of Xs/Ys rows
#define HSTR 68      // float stride of H-plane rows
#define NTHREADS 512

#define C1c 1.0e-4f  // (0.01*DR)^2
#define C2c 9.0e-4f  // (0.03*DR)^2

__device__ __forceinline__ float bf2f(unsigned short h) {
  union { unsigned int u; float f; } c; c.u = ((unsigned int)h) << 16; return c.f;
}
__device__ __forceinline__ unsigned short f2bf(float f) {
  union { float f; unsigned int u; } c; c.f = f;
  unsigned int r = (c.u + 0x7FFFu + ((c.u >> 16) & 1u)) >> 16;
  return (unsigned short)r;
}

__device__ __forceinline__ void unpack8(uint4 u, float* v) {
  union { unsigned int u32; float f; } c;
  c.u32 = u.x << 16;         v[0] = c.f;
  c.u32 = u.x & 0xFFFF0000u; v[1] = c.f;
  c.u32 = u.y << 16;         v[2] = c.f;
  c.u32 = u.y & 0xFFFF0000u; v[3] = c.f;
  c.u32 = u.z << 16;         v[4] = c.f;
  c.u32 = u.z & 0xFFFF0000u; v[5] = c.f;
  c.u32 = u.w << 16;         v[6] = c.f;
  c.u32 = u.w & 0xFFFF0000u; v[7] = c.f;
}

template<int NV>
__device__ __forceinline__ void load_win(const unsigned short* p, float* v) {
  const uint4* q = (const uint4*)p;
  #pragma unroll
  for (int j = 0; j < NV; ++j) { uint4 u = q[j]; unpack8(u, v + 8 * j); }
}

// Horizontal pass. Q: 0=x, 1=y, 2=x*x, 3=y*y, 4=x*y, 5=|x-y|
template<int R, int Q>
__device__ __forceinline__ void hpass(const unsigned short* __restrict__ Xs,
                                      const unsigned short* __restrict__ Ys,
                                      float* __restrict__ Hs,
                                      const float* __restrict__ w, int tid) {
  constexpr int START = HALO - R;          // leftmost rel. input col for colgroup 0
  constexpr int ABASE = START & ~7;        // align to 8 bf16 (16B)
  constexpr int OFF   = START - ABASE;
  constexpr int WIN   = 2 * R + 8;         // window floats per 8 outputs
  constexpr int NV    = (OFF + WIN + 7) >> 3;
  constexpr int NE    = NV * 8;
  constexpr int ROWS  = TILE + 2 * R;      // rows the V-pass will consume
  constexpr int NS    = 8 * ROWS;          // strips (8 colgroups x ROWS)
  static_assert(OFF + 7 + 2 * R <= NE - 1, "window fits");
  for (int s = tid; s < NS; s += NTHREADS) {
    const int g = s & 7;
    const int r = (s >> 3) + (HALO - R);
    const int base = r * XSTR + ABASE + g * 8;
    float v[NE];
    if (Q == 0 || Q == 2) {
      load_win<NV>(Xs + base, v);
      if (Q == 2) {
        #pragma unroll
        for (int j = 0; j < NE; ++j) v[j] *= v[j];
      }
    } else if (Q == 1 || Q == 3) {
      load_win<NV>(Ys + base, v);
      if (Q == 3) {
        #pragma unroll
        for (int j = 0; j < NE; ++j) v[j] *= v[j];
      }
    } else {
      float vy[NE];
      load_win<NV>(Xs + base, v);
      load_win<NV>(Ys + base, vy);
      if (Q == 4) {
        #pragma unroll
        for (int j = 0; j < NE; ++j) v[j] *= vy[j];
      } else {
        #pragma unroll
        for (int j = 0; j < NE; ++j) v[j] = fabsf(v[j] - vy[j]);
      }
    }
    float acc[8] = {0.f,0.f,0.f,0.f,0.f,0.f,0.f,0.f};
    #pragma unroll
    for (int k = 0; k <= 2 * R; ++k) {
      #pragma unroll
      for (int o = 0; o < 8; ++o)
        acc[o] = fmaf(w[k], v[OFF + o + k], acc[o]);
    }
    float4* dst = (float4*)(Hs + r * HSTR + g * 8);
    dst[0] = make_float4(acc[0], acc[1], acc[2], acc[3]);
    dst[1] = make_float4(acc[4], acc[5], acc[6], acc[7]);
  }
}

template<int R>
__device__ __forceinline__ void vpass(const float* __restrict__ Hs,
                                      const float* __restrict__ w,
                                      int tid, float* __restrict__ out) {
  const int c  = tid & 63;
  const int rg = tid >> 6;
  const int rbase = rg * 8 + HALO - R;
  float acc[8] = {0.f,0.f,0.f,0.f,0.f,0.f,0.f,0.f};
  #pragma unroll
  for (int i = 0; i < 2 * R + 8; ++i) {
    float hv = Hs[(rbase + i) * HSTR + c];
    #pragma unroll
    for (int o = 0; o < 8; ++o) {
      if (i - o >= 0 && i - o <= 2 * R)
        acc[o] = fmaf(w[i - o], hv, acc[o]);
    }
  }
  #pragma unroll
  for (int o = 0; o < 8; ++o) out[o] = acc[o];
}

template<int R>
__device__ __forceinline__ void mkweights(float sigma, float* w) {
  const float inv = 1.0f / (2.0f * sigma * sigma);
  float s = 0.0f;
  for (int k = -16; k <= 16; ++k) s += expf(-(float)(k * k) * inv);
  const float si = 1.0f / s;
  #pragma unroll
  for (int k = 0; k <= 2 * R; ++k) {
    const int d = k - R;
    w[k] = expf(-(float)(d * d) * inv) * si;
  }
}

template<int R>
__device__ __forceinline__ void do_sigma(float sigma, int mult, bool last,
                                         const unsigned short* Xs,
                                         const unsigned short* Ys,
                                         float* Hs, int tid,
                                         float* PIcs, float* lM) {
  float w[2 * R + 1];
  mkweights<R>(sigma, w);
  float r0[8], r1[8], r2[8], r3[8], r4[8];
  hpass<R,0>(Xs, Ys, Hs, w, tid); __syncthreads(); vpass<R>(Hs, w, tid, r0); __syncthreads();
  hpass<R,1>(Xs, Ys, Hs, w, tid); __syncthreads(); vpass<R>(Hs, w, tid, r1); __syncthreads();
  hpass<R,2>(Xs, Ys, Hs, w, tid); __syncthreads(); vpass<R>(Hs, w, tid, r2); __syncthreads();
  hpass<R,3>(Xs, Ys, Hs, w, tid); __syncthreads(); vpass<R>(Hs, w, tid, r3); __syncthreads();
  hpass<R,4>(Xs, Ys, Hs, w, tid); __syncthreads(); vpass<R>(Hs, w, tid, r4); __syncthreads();
  #pragma unroll
  for (int i = 0; i < 8; ++i) {
    const float mux = r0[i], muy = r1[i];
    const float sx2 = r2[i] - mux * mux;
    const float sy2 = r3[i] - muy * muy;
    const float sxy = r4[i] - mux * muy;
    const float cs = (2.f * sxy + C2c) / (sx2 + sy2 + C2c);
    float p = cs;
    if (mult >= 2) p *= cs;
    if (mult >= 3) p *= cs;
    PIcs[i] *= p;
    if (last) {
      const float l = (2.f * mux * muy + C1c) / (mux * mux + muy * muy + C1c);
      lM[i] *= l * l * l;
    }
  }
}

template<int R>
__device__ __forceinline__ void do_l1(float sigma,
                                      const unsigned short* Xs,
                                      const unsigned short* Ys,
                                      float* Hs, int tid, float* gl1) {
  float w[2 * R + 1];
  mkweights<R>(sigma, w);
  float rr[8];
  hpass<R,5>(Xs, Ys, Hs, w, tid); __syncthreads(); vpass<R>(Hs, w, tid, rr); __syncthreads();
  #pragma unroll
  for (int i = 0; i < 8; ++i) gl1[i] += rr[i];
}

__global__ __launch_bounds__(NTHREADS)
void msssim_fused_kernel(const float* __restrict__ x, const float* __restrict__ y,
                         float* __restrict__ partials) {
  __shared__ unsigned short Xs[HA * XSTR];
  __shared__ unsigned short Ys[HA * XSTR];
  __shared__ float Hs[HA * HSTR];
  __shared__ float red[16];

  const int tid = threadIdx.x;
  const int bx = blockIdx.x, by = blockIdx.y, b = blockIdx.z;
  const int y0 = by * TILE - HALO;
  const int x0 = bx * TILE - HALO;

  float PIcs[8], lM[8], gl1[8];
  #pragma unroll
  for (int i = 0; i < 8; ++i) { PIcs[i] = 1.f; lM[i] = 1.f; gl1[i] = 0.f; }
  float absacc = 0.f;

  for (int ch = 0; ch < 3; ++ch) {
    __syncthreads();   // protect Xs/Ys from prior channel readers
    const float* __restrict__ xs = x + (size_t)(b * 3 + ch) * 512 * 512;
    const float* __restrict__ ys = y + (size_t)(b * 3 + ch) * 512 * 512;
    for (int idx = tid; idx < HA * HA; idx += NTHREADS) {
      const int r  = idx / HA;
      const int cc = idx - r * HA;
      const int gy = y0 + r, gx = x0 + cc;
      const bool ok = (gy >= 0) && (gy < 512) && (gx >= 0) && (gx < 512);
      float xv = 0.f, yv = 0.f;
      if (ok) { xv = xs[gy * 512 + gx] * 0.5f + 0.5f; yv = ys[gy * 512 + gx] * 0.5f + 0.5f; }
      Xs[idx] = ok ? f2bf(xv) : (unsigned short)0;
      Ys[idx] = ok ? f2bf(yv) : (unsigned short)0;
    }
    __syncthreads();

    { // plain per-pixel |x-y| for gen-loss L1 (denormalized x,y)
      const int c = tid & 63, rg = tid >> 6;
      #pragma unroll
      for (int i = 0; i < 8; ++i) {
        const int hidx = (HALO + rg * 8 + i) * XSTR + HALO + c;
        absacc += fabsf(bf2f(Xs[hidx]) - bf2f(Ys[hidx]));
      }
    }

    if (ch == 0) {
      do_sigma<4>(0.5f, 3, false, Xs, Ys, Hs, tid, PIcs, lM);
      do_sigma<7>(1.0f, 2, false, Xs, Ys, Hs, tid, PIcs, lM);
      do_l1<16>(8.0f, Xs, Ys, Hs, tid, gl1);
    } else if (ch == 1) {
      do_sigma<7>(1.0f, 1, false, Xs, Ys, Hs, tid, PIcs, lM);
      do_sigma<13>(2.0f, 3, false, Xs, Ys, Hs, tid, PIcs, lM);
      do_sigma<16>(4.0f, 1, false, Xs, Ys, Hs, tid, PIcs, lM);
      do_l1<16>(8.0f, Xs, Ys, Hs, tid, gl1);
    } else {
      do_sigma<16>(4.0f, 2, false, Xs, Ys, Hs, tid, PIcs, lM);
      do_sigma<16>(8.0f, 3, true, Xs, Ys, Hs, tid, PIcs, lM);
      do_l1<16>(8.0f, Xs, Ys, Hs, tid, gl1);
    }
  }

  float mixsum = 0.f;
  #pragma unroll
  for (int i = 0; i < 8; ++i) {
    const float ssim = 1.f - lM[i] * PIcs[i];
    mixsum += 200.f * (0.025f * ssim + 0.975f * (gl1[i] * (1.f / 3.f)));
  }

  // block reduction of mixsum and absacc
  #pragma unroll
  for (int off = 32; off > 0; off >>= 1) {
    mixsum += __shfl_down(mixsum, off);
    absacc += __shfl_down(absacc, off);
  }
  const int wave = tid >> 6, lane = tid & 63;
  if (lane == 0) { red[wave] = mixsum; red[8 + wave] = absacc; }
  __syncthreads();
  if (tid == 0) {
    float m = 0.f, a = 0.f;
    #pragma unroll
    for (int i = 0; i < 8; ++i) { m += red[i]; a += red[8 + i]; }
    const int blk = (b * 8 + by) * 8 + bx;
    partials[2 * blk + 0] = m;
    partials[2 * blk + 1] = a;
  }
}

__global__ __launch_bounds__(512)
void msssim_final_kernel(const float* __restrict__ partials,
                         const float* __restrict__ disc,
                         float* __restrict__ out) {
  __shared__ float red[24];
  const int tid = threadIdx.x;
  float m = 0.f, a = 0.f, d2 = 0.f;
  { // exactly one partial pair per thread (512 blocks, 512 threads)
    m = partials[2 * tid + 0];
    a = partials[2 * tid + 1];
  }
  for (int i = tid; i < 8 * 62 * 62; i += 512) {
    const float d = disc[i] - 1.f;
    d2 = fmaf(d, d, d2);
  }
  #pragma unroll
  for (int off = 32; off > 0; off >>= 1) {
    m  += __shfl_down(m, off);
    a  += __shfl_down(a, off);
    d2 += __shfl_down(d2, off);
  }
  const int wave = tid >> 6, lane = tid & 63;
  if (lane == 0) { red[wave] = m; red[8 + wave] = a; red[16 + wave] = d2; }
  __syncthreads();
  if (tid == 0) {
    float sm = 0.f, sa = 0.f, sd = 0.f;
    #pragma unroll
    for (int i = 0; i < 8; ++i) { sm += red[i]; sa += red[8 + i]; sd += red[16 + i]; }
    const float mix_mean  = sm / (8.f * 512.f * 512.f);
    const float abs_mean  = sa / (8.f * 3.f * 512.f * 512.f);
    const float disc_mean = sd / (8.f * 62.f * 62.f);
    out[0] = 0.5f * (mix_mean + 100.f * abs_mean + disc_mean);
  }
}

extern "C" void kernel_launch(void* const* d_in, const int* in_sizes, int n_in,
                              void* d_out, int out_size, void* d_ws, size_t ws_size,
                              hipStream_t stream) {
  const float* x    = (const float*)d_in[0];
  const float* y    = (const float*)d_in[1];
  const float* disc = (const float*)d_in[2];
  // d_in[3] = g_masks (unused: weights are recomputed exactly on device)
  float* partials = (float*)d_ws;   // 512 * 2 floats, fully overwritten each call
  dim3 grid(8, 8, 8);
  msssim_fused_kernel<<<grid, NTHREADS, 0, stream>>>(x, y, partials);
  msssim_final_kernel<<<1, 512, 0, stream>>>(partials, disc, (float*)d_out);
}

// Round 2
// 520.311 us; speedup vs baseline: 1.6396x; 1.6396x over previous
//
#include <hip/hip_runtime.h>
#include <stdint.h>

// MS-SSIM + L1 fused loss, MI355X.
// R1 change: streaming H-pass (no full-window register arrays -> no scratch
// spills; R0 spilled ~1GB/launch to scratch, WRITE_SIZE 522MB) + weights
// hinted into SGPRs via readfirstlane.

#define TILE 64
#define HALO 16
#define HA   96      // halo extent (TILE + 2*HALO)
#define XSTR 96      // ushort stride of Xs/Ys rows
#define HSTR 68      // float stride of H-plane rows
#define NTHREADS 512

#define C1c 1.0e-4f  // (0.01*DR)^2
#define C2c 9.0e-4f  // (0.03*DR)^2

__device__ __forceinline__ float bf2f(unsigned short h) {
  union { unsigned int u; float f; } c; c.u = ((unsigned int)h) << 16; return c.f;
}
__device__ __forceinline__ unsigned short f2bf(float f) {
  union { float f; unsigned int u; } c; c.f = f;
  unsigned int r = (c.u + 0x7FFFu + ((c.u >> 16) & 1u)) >> 16;
  return (unsigned short)r;
}
__device__ __forceinline__ float uniform_f(float x) {
  union { float f; int i; } c; c.f = x;
  c.i = __builtin_amdgcn_readfirstlane(c.i);
  return c.f;
}

__device__ __forceinline__ void unpack8(uint4 u, float* v) {
  union { unsigned int u32; float f; } c;
  c.u32 = u.x << 16;         v[0] = c.f;
  c.u32 = u.x & 0xFFFF0000u; v[1] = c.f;
  c.u32 = u.y << 16;         v[2] = c.f;
  c.u32 = u.y & 0xFFFF0000u; v[3] = c.f;
  c.u32 = u.z << 16;         v[4] = c.f;
  c.u32 = u.z & 0xFFFF0000u; v[5] = c.f;
  c.u32 = u.w << 16;         v[6] = c.f;
  c.u32 = u.w & 0xFFFF0000u; v[7] = c.f;
}

// Horizontal pass, streaming form. Q: 0=x, 1=y, 2=x*x, 3=y*y, 4=x*y, 5=|x-y|
template<int R, int Q>
__device__ __forceinline__ void hpass(const unsigned short* __restrict__ Xs,
                                      const unsigned short* __restrict__ Ys,
                                      float* __restrict__ Hs,
                                      const float* __restrict__ w, int tid) {
  constexpr int START = HALO - R;          // leftmost rel. input col for colgroup 0
  constexpr int ABASE = START & ~7;        // align to 8 bf16 (16B)
  constexpr int OFF   = START - ABASE;
  constexpr int WIN   = 2 * R + 8;         // window floats per 8 outputs
  constexpr int NV    = (OFF + WIN + 7) >> 3;
  constexpr int ROWS  = TILE + 2 * R;      // rows the V-pass will consume
  constexpr int NS    = 8 * ROWS;          // strips (8 colgroups x ROWS)
  static_assert(OFF + 7 + 2 * R <= NV * 8 - 1, "window fits");
  for (int s = tid; s < NS; s += NTHREADS) {
    const int g = s & 7;
    const int r = (s >> 3) + (HALO - R);
    const int base = r * XSTR + ABASE + g * 8;
    const uint4* qx = (const uint4*)(Xs + base);
    const uint4* qy = (const uint4*)(Ys + base);
    float acc[8] = {0.f,0.f,0.f,0.f,0.f,0.f,0.f,0.f};
    #pragma unroll
    for (int j = 0; j < NV; ++j) {
      float val[8];
      if (Q == 0) {
        unpack8(qx[j], val);
      } else if (Q == 1) {
        unpack8(qy[j], val);
      } else if (Q == 2) {
        unpack8(qx[j], val);
        #pragma unroll
        for (int jj = 0; jj < 8; ++jj) val[jj] *= val[jj];
      } else if (Q == 3) {
        unpack8(qy[j], val);
        #pragma unroll
        for (int jj = 0; jj < 8; ++jj) val[jj] *= val[jj];
      } else {
        float vy[8];
        unpack8(qx[j], val);
        unpack8(qy[j], vy);
        if (Q == 4) {
          #pragma unroll
          for (int jj = 0; jj < 8; ++jj) val[jj] *= vy[jj];
        } else {
          #pragma unroll
          for (int jj = 0; jj < 8; ++jj) val[jj] = fabsf(val[jj] - vy[jj]);
        }
      }
      #pragma unroll
      for (int jj = 0; jj < 8; ++jj) {
        const int k = j * 8 + jj;        // window index (compile-time)
        #pragma unroll
        for (int o = 0; o < 8; ++o) {
          const int wi = k - OFF - o;    // tap index (compile-time)
          if (wi >= 0 && wi <= 2 * R)
            acc[o] = fmaf(w[wi], val[jj], acc[o]);
        }
      }
    }
    float4* dst = (float4*)(Hs + r * HSTR + g * 8);
    dst[0] = make_float4(acc[0], acc[1], acc[2], acc[3]);
    dst[1] = make_float4(acc[4], acc[5], acc[6], acc[7]);
  }
}

template<int R>
__device__ __forceinline__ void vpass(const float* __restrict__ Hs,
                                      const float* __restrict__ w,
                                      int tid, float* __restrict__ out) {
  const int c  = tid & 63;
  const int rg = tid >> 6;
  const int rbase = rg * 8 + HALO - R;
  float acc[8] = {0.f,0.f,0.f,0.f,0.f,0.f,0.f,0.f};
  #pragma unroll
  for (int i = 0; i < 2 * R + 8; ++i) {
    float hv = Hs[(rbase + i) * HSTR + c];
    #pragma unroll
    for (int o = 0; o < 8; ++o) {
      if (i - o >= 0 && i - o <= 2 * R)
        acc[o] = fmaf(w[i - o], hv, acc[o]);
    }
  }
  #pragma unroll
  for (int o = 0; o < 8; ++o) out[o] = acc[o];
}

template<int R>
__device__ __forceinline__ void mkweights(float sigma, float* w) {
  const float inv = 1.0f / (2.0f * sigma * sigma);
  float s = 0.0f;
  for (int k = -16; k <= 16; ++k) s += expf(-(float)(k * k) * inv);
  const float si = 1.0f / s;
  #pragma unroll
  for (int k = 0; k <= 2 * R; ++k) {
    const int d = k - R;
    w[k] = uniform_f(expf(-(float)(d * d) * inv) * si);
  }
}

template<int R>
__device__ __forceinline__ void do_sigma(float sigma, int mult, bool last,
                                         const unsigned short* Xs,
                                         const unsigned short* Ys,
                                         float* Hs, int tid,
                                         float* PIcs, float* lM) {
  float w[2 * R + 1];
  mkweights<R>(sigma, w);
  float r0[8], r1[8], r2[8], r3[8], r4[8];
  hpass<R,0>(Xs, Ys, Hs, w, tid); __syncthreads(); vpass<R>(Hs, w, tid, r0); __syncthreads();
  hpass<R,1>(Xs, Ys, Hs, w, tid); __syncthreads(); vpass<R>(Hs, w, tid, r1); __syncthreads();
  hpass<R,2>(Xs, Ys, Hs, w, tid); __syncthreads(); vpass<R>(Hs, w, tid, r2); __syncthreads();
  hpass<R,3>(Xs, Ys, Hs, w, tid); __syncthreads(); vpass<R>(Hs, w, tid, r3); __syncthreads();
  hpass<R,4>(Xs, Ys, Hs, w, tid); __syncthreads(); vpass<R>(Hs, w, tid, r4); __syncthreads();
  #pragma unroll
  for (int i = 0; i < 8; ++i) {
    const float mux = r0[i], muy = r1[i];
    const float sx2 = r2[i] - mux * mux;
    const float sy2 = r3[i] - muy * muy;
    const float sxy = r4[i] - mux * muy;
    const float cs = (2.f * sxy + C2c) / (sx2 + sy2 + C2c);
    float p = cs;
    if (mult >= 2) p *= cs;
    if (mult >= 3) p *= cs;
    PIcs[i] *= p;
    if (last) {
      const float l = (2.f * mux * muy + C1c) / (mux * mux + muy * muy + C1c);
      lM[i] *= l * l * l;
    }
  }
}

template<int R>
__device__ __forceinline__ void do_l1(float sigma,
                                      const unsigned short* Xs,
                                      const unsigned short* Ys,
                                      float* Hs, int tid, float* gl1) {
  float w[2 * R + 1];
  mkweights<R>(sigma, w);
  float rr[8];
  hpass<R,5>(Xs, Ys, Hs, w, tid); __syncthreads(); vpass<R>(Hs, w, tid, rr); __syncthreads();
  #pragma unroll
  for (int i = 0; i < 8; ++i) gl1[i] += rr[i];
}

__global__ __launch_bounds__(NTHREADS)
void msssim_fused_kernel(const float* __restrict__ x, const float* __restrict__ y,
                         float* __restrict__ partials) {
  __shared__ unsigned short Xs[HA * XSTR];
  __shared__ unsigned short Ys[HA * XSTR];
  __shared__ float Hs[HA * HSTR];
  __shared__ float red[16];

  const int tid = threadIdx.x;
  const int bx = blockIdx.x, by = blockIdx.y, b = blockIdx.z;
  const int y0 = by * TILE - HALO;
  const int x0 = bx * TILE - HALO;

  float PIcs[8], lM[8], gl1[8];
  #pragma unroll
  for (int i = 0; i < 8; ++i) { PIcs[i] = 1.f; lM[i] = 1.f; gl1[i] = 0.f; }
  float absacc = 0.f;

  for (int ch = 0; ch < 3; ++ch) {
    __syncthreads();   // protect Xs/Ys from prior channel readers
    const float* __restrict__ xs = x + (size_t)(b * 3 + ch) * 512 * 512;
    const float* __restrict__ ys = y + (size_t)(b * 3 + ch) * 512 * 512;
    for (int idx = tid; idx < HA * HA; idx += NTHREADS) {
      const int r  = idx / HA;
      const int cc = idx - r * HA;
      const int gy = y0 + r, gx = x0 + cc;
      const bool ok = (gy >= 0) && (gy < 512) && (gx >= 0) && (gx < 512);
      float xv = 0.f, yv = 0.f;
      if (ok) { xv = xs[gy * 512 + gx] * 0.5f + 0.5f; yv = ys[gy * 512 + gx] * 0.5f + 0.5f; }
      Xs[idx] = ok ? f2bf(xv) : (unsigned short)0;
      Ys[idx] = ok ? f2bf(yv) : (unsigned short)0;
    }
    __syncthreads();

    { // plain per-pixel |x-y| for gen-loss L1 (denormalized x,y)
      const int c = tid & 63, rg = tid >> 6;
      #pragma unroll
      for (int i = 0; i < 8; ++i) {
        const int hidx = (HALO + rg * 8 + i) * XSTR + HALO + c;
        absacc += fabsf(bf2f(Xs[hidx]) - bf2f(Ys[hidx]));
      }
    }

    if (ch == 0) {
      do_sigma<4>(0.5f, 3, false, Xs, Ys, Hs, tid, PIcs, lM);
      do_sigma<7>(1.0f, 2, false, Xs, Ys, Hs, tid, PIcs, lM);
      do_l1<16>(8.0f, Xs, Ys, Hs, tid, gl1);
    } else if (ch == 1) {
      do_sigma<7>(1.0f, 1, false, Xs, Ys, Hs, tid, PIcs, lM);
      do_sigma<13>(2.0f, 3, false, Xs, Ys, Hs, tid, PIcs, lM);
      do_sigma<16>(4.0f, 1, false, Xs, Ys, Hs, tid, PIcs, lM);
      do_l1<16>(8.0f, Xs, Ys, Hs, tid, gl1);
    } else {
      do_sigma<16>(4.0f, 2, false, Xs, Ys, Hs, tid, PIcs, lM);
      do_sigma<16>(8.0f, 3, true, Xs, Ys, Hs, tid, PIcs, lM);
      do_l1<16>(8.0f, Xs, Ys, Hs, tid, gl1);
    }
  }

  float mixsum = 0.f;
  #pragma unroll
  for (int i = 0; i < 8; ++i) {
    const float ssim = 1.f - lM[i] * PIcs[i];
    mixsum += 200.f * (0.025f * ssim + 0.975f * (gl1[i] * (1.f / 3.f)));
  }

  // block reduction of mixsum and absacc
  #pragma unroll
  for (int off = 32; off > 0; off >>= 1) {
    mixsum += __shfl_down(mixsum, off);
    absacc += __shfl_down(absacc, off);
  }
  const int wave = tid >> 6, lane = tid & 63;
  if (lane == 0) { red[wave] = mixsum; red[8 + wave] = absacc; }
  __syncthreads();
  if (tid == 0) {
    float m = 0.f, a = 0.f;
    #pragma unroll
    for (int i = 0; i < 8; ++i) { m += red[i]; a += red[8 + i]; }
    const int blk = (b * 8 + by) * 8 + bx;
    partials[2 * blk + 0] = m;
    partials[2 * blk + 1] = a;
  }
}

__global__ __launch_bounds__(512)
void msssim_final_kernel(const float* __restrict__ partials,
                         const float* __restrict__ disc,
                         float* __restrict__ out) {
  __shared__ float red[24];
  const int tid = threadIdx.x;
  float m = 0.f, a = 0.f, d2 = 0.f;
  { // exactly one partial pair per thread (512 blocks, 512 threads)
    m = partials[2 * tid + 0];
    a = partials[2 * tid + 1];
  }
  for (int i = tid; i < 8 * 62 * 62; i += 512) {
    const float d = disc[i] - 1.f;
    d2 = fmaf(d, d, d2);
  }
  #pragma unroll
  for (int off = 32; off > 0; off >>= 1) {
    m  += __shfl_down(m, off);
    a  += __shfl_down(a, off);
    d2 += __shfl_down(d2, off);
  }
  const int wave = tid >> 6, lane = tid & 63;
  if (lane == 0) { red[wave] = m; red[8 + wave] = a; red[16 + wave] = d2; }
  __syncthreads();
  if (tid == 0) {
    float sm = 0.f, sa = 0.f, sd = 0.f;
    #pragma unroll
    for (int i = 0; i < 8; ++i) { sm += red[i]; sa += red[8 + i]; sd += red[16 + i]; }
    const float mix_mean  = sm / (8.f * 512.f * 512.f);
    const float abs_mean  = sa / (8.f * 3.f * 512.f * 512.f);
    const float disc_mean = sd / (8.f * 62.f * 62.f);
    out[0] = 0.5f * (mix_mean + 100.f * abs_mean + disc_mean);
  }
}

extern "C" void kernel_launch(void* const* d_in, const int* in_sizes, int n_in,
                              void* d_out, int out_size, void* d_ws, size_t ws_size,
                              hipStream_t stream) {
  const float* x    = (const float*)d_in[0];
  const float* y    = (const float*)d_in[1];
  const float* disc = (const float*)d_in[2];
  // d_in[3] = g_masks (unused: weights are recomputed exactly on device)
  float* partials = (float*)d_ws;   // 512 * 2 floats, fully overwritten each call
  dim3 grid(8, 8, 8);
  msssim_fused_kernel<<<grid, NTHREADS, 0, stream>>>(x, y, partials);
  msssim_final_kernel<<<1, 512, 0, stream>>>(partials, disc, (float*)d_out);
}